// Round 1
// baseline (188.345 us; speedup 1.0000x reference)
//
#include <hip/hip_runtime.h>
#include <hip/hip_bf16.h>

#define B_ 8
#define Q_ 128
#define K_ 256
#define D_ 512

#if __has_builtin(__builtin_amdgcn_exp2f)
#define EX2 __builtin_amdgcn_exp2f
#else
#define EX2 exp2f
#endif
#if __has_builtin(__builtin_amdgcn_rcpf)
#define RCP __builtin_amdgcn_rcpf
#else
#define RCP(x) (1.0f / (x))
#endif

__device__ __forceinline__ float tanh_fast(float x) {
  // tanh(x) = 1 - 2/(exp(2x)+1); exp(2x) = exp2(x * 2*log2(e))
  float e = EX2(x * 2.8853900817779268f);
  return fmaf(-2.0f, RCP(e + 1.0f), 1.0f);
}

// ---------------- Kernel 1: projections ----------------
// rows 0..1023   : qp[row][h]  = sum_d query[row][d] * W1[d][h]
// rows 1024..3071: kpb[row][h] = sum_d key[row][d] * W1[512+d][h] + b1[h]
__global__ __launch_bounds__(256) void proj_kernel(
    const float* __restrict__ query, const float* __restrict__ key,
    const float* __restrict__ W1, const float* __restrict__ b1,
    float* __restrict__ qp, float* __restrict__ kpb) {
  __shared__ float xs[8][D_];
  const int t = threadIdx.x;
  const int block_row0 = blockIdx.x * 8;
  const bool is_k = block_row0 >= B_ * Q_;
  const float* X = is_k ? key : query;
  const int row0 = is_k ? (block_row0 - B_ * Q_) : block_row0;
  const float* W = W1 + (is_k ? (size_t)D_ * D_ : 0);
  float* out = is_k ? kpb : qp;

  {
    const float4* src = (const float4*)(X + (size_t)row0 * D_);
    float4* dst = (float4*)(&xs[0][0]);
#pragma unroll
    for (int i = 0; i < 4; ++i) dst[t + 256 * i] = src[t + 256 * i];
  }
  __syncthreads();

  float acc0[8] = {0.f, 0.f, 0.f, 0.f, 0.f, 0.f, 0.f, 0.f};
  float acc1[8] = {0.f, 0.f, 0.f, 0.f, 0.f, 0.f, 0.f, 0.f};
  for (int d = 0; d < D_; d += 4) {
    float xr[8][4];
#pragma unroll
    for (int r = 0; r < 8; ++r) {
      float4 tmp = *(const float4*)&xs[r][d];
      xr[r][0] = tmp.x; xr[r][1] = tmp.y; xr[r][2] = tmp.z; xr[r][3] = tmp.w;
    }
#pragma unroll
    for (int dd = 0; dd < 4; ++dd) {
      float w0 = W[(size_t)(d + dd) * D_ + t];
      float w1 = W[(size_t)(d + dd) * D_ + t + 256];
#pragma unroll
      for (int r = 0; r < 8; ++r) {
        acc0[r] = fmaf(xr[r][dd], w0, acc0[r]);
        acc1[r] = fmaf(xr[r][dd], w1, acc1[r]);
      }
    }
  }
  float bb0 = 0.f, bb1 = 0.f;
  if (is_k) { bb0 = b1[t]; bb1 = b1[t + 256]; }
#pragma unroll
  for (int r = 0; r < 8; ++r) {
    out[(size_t)(row0 + r) * D_ + t] = acc0[r] + bb0;
    out[(size_t)(row0 + r) * D_ + t + 256] = acc1[r] + bb1;
  }
}

// ---------------- Kernel 2: fused tanh-score + softmax + PV ----------------
// grid (Q_/2, B_), block 256 threads (4 waves). Block handles (b, q0..q0+1).
__global__ __launch_bounds__(256) void attn_kernel(
    const float* __restrict__ qp, const float* __restrict__ kpb,
    const float* __restrict__ value, const int* __restrict__ mask,
    const float* __restrict__ w2,
    float* __restrict__ out_vec, float* __restrict__ out_w) {
  const int b = blockIdx.y;
  const int q0 = blockIdx.x * 2;
  const int t = threadIdx.x;
  const int lane = t & 63;
  const int wave = t >> 6;
  const float scale = 0.044194173824159216f;  // 1/sqrt(512)

  __shared__ float sc[2][K_];

  // lane covers h = lane*8 .. lane*8+7
  float qpr[2][8], w2r[8];
  {
    const float4* q40 = (const float4*)(qp + (size_t)(b * Q_ + q0) * D_);
    const float4* q41 = (const float4*)(qp + (size_t)(b * Q_ + q0 + 1) * D_);
    const float4* wv = (const float4*)w2;
    float4 a0 = q40[lane * 2], a1 = q40[lane * 2 + 1];
    float4 b0 = q41[lane * 2], b1v = q41[lane * 2 + 1];
    float4 c0 = wv[lane * 2], c1 = wv[lane * 2 + 1];
    qpr[0][0] = a0.x; qpr[0][1] = a0.y; qpr[0][2] = a0.z; qpr[0][3] = a0.w;
    qpr[0][4] = a1.x; qpr[0][5] = a1.y; qpr[0][6] = a1.z; qpr[0][7] = a1.w;
    qpr[1][0] = b0.x; qpr[1][1] = b0.y; qpr[1][2] = b0.z; qpr[1][3] = b0.w;
    qpr[1][4] = b1v.x; qpr[1][5] = b1v.y; qpr[1][6] = b1v.z; qpr[1][7] = b1v.w;
    w2r[0] = c0.x; w2r[1] = c0.y; w2r[2] = c0.z; w2r[3] = c0.w;
    w2r[4] = c1.x; w2r[5] = c1.y; w2r[6] = c1.z; w2r[7] = c1.w;
  }

  // Phase 1: scores. Wave w handles k in [w*64, w*64+64)
  const float* kb = kpb + (size_t)b * K_ * D_;
  const int kbeg = wave * 64;
  for (int k = kbeg; k < kbeg + 64; ++k) {
    const float4* kr = (const float4*)(kb + (size_t)k * D_);
    float4 c0 = kr[lane * 2], c1 = kr[lane * 2 + 1];
    float kv[8] = {c0.x, c0.y, c0.z, c0.w, c1.x, c1.y, c1.z, c1.w};
    float a0 = 0.f, a1 = 0.f;
#pragma unroll
    for (int j = 0; j < 8; ++j) {
      a0 = fmaf(w2r[j], tanh_fast(qpr[0][j] + kv[j]), a0);
      a1 = fmaf(w2r[j], tanh_fast(qpr[1][j] + kv[j]), a1);
    }
#pragma unroll
    for (int off = 32; off > 0; off >>= 1) {
      a0 += __shfl_xor(a0, off, 64);
      a1 += __shfl_xor(a1, off, 64);
    }
    const bool m = mask[b * K_ + k] != 0;
    if (lane == 0) {
      sc[0][k] = (m ? -1.0e9f : a0) * scale;
      sc[1][k] = (m ? -1.0e9f : a1) * scale;
    }
  }
  __syncthreads();

  // Phase 2: softmax (wave 0 -> q0, wave 1 -> q0+1)
  if (wave < 2) {
    const int q = wave;
    float v0 = sc[q][lane], v1 = sc[q][lane + 64];
    float v2 = sc[q][lane + 128], v3 = sc[q][lane + 192];
    float mx = fmaxf(fmaxf(v0, v1), fmaxf(v2, v3));
#pragma unroll
    for (int off = 32; off > 0; off >>= 1) mx = fmaxf(mx, __shfl_xor(mx, off, 64));
    const float L2E = 1.4426950408889634f;
    float e0 = EX2((v0 - mx) * L2E), e1 = EX2((v1 - mx) * L2E);
    float e2 = EX2((v2 - mx) * L2E), e3 = EX2((v3 - mx) * L2E);
    float s = e0 + e1 + e2 + e3;
#pragma unroll
    for (int off = 32; off > 0; off >>= 1) s += __shfl_xor(s, off, 64);
    float inv = RCP(s);
    float p0 = e0 * inv, p1 = e1 * inv, p2 = e2 * inv, p3 = e3 * inv;
    sc[q][lane] = p0; sc[q][lane + 64] = p1;
    sc[q][lane + 128] = p2; sc[q][lane + 192] = p3;
    float* ow = out_w + (size_t)(b * Q_ + q0 + q) * K_;
    ow[lane] = p0; ow[lane + 64] = p1; ow[lane + 128] = p2; ow[lane + 192] = p3;
  }
  __syncthreads();

  // Phase 3: attn_vec = weights @ value. Thread t -> cols t, t+256.
  float acc00 = 0.f, acc01 = 0.f, acc10 = 0.f, acc11 = 0.f;
  const float* vb = value + (size_t)b * K_ * D_;
  for (int k = 0; k < K_; ++k) {
    float w0 = sc[0][k], w1 = sc[1][k];
    float v0 = vb[(size_t)k * D_ + t];
    float v1 = vb[(size_t)k * D_ + t + 256];
    acc00 = fmaf(w0, v0, acc00);
    acc01 = fmaf(w0, v1, acc01);
    acc10 = fmaf(w1, v0, acc10);
    acc11 = fmaf(w1, v1, acc11);
  }
  float* o0 = out_vec + (size_t)(b * Q_ + q0) * D_;
  float* o1 = out_vec + (size_t)(b * Q_ + q0 + 1) * D_;
  o0[t] = acc00; o0[t + 256] = acc01;
  o1[t] = acc10; o1[t + 256] = acc11;
}

extern "C" void kernel_launch(void* const* d_in, const int* in_sizes, int n_in,
                              void* d_out, int out_size, void* d_ws, size_t ws_size,
                              hipStream_t stream) {
  const float* query = (const float*)d_in[0];
  const float* key   = (const float*)d_in[1];
  const float* value = (const float*)d_in[2];
  const int*   mask  = (const int*)d_in[3];
  const float* W1    = (const float*)d_in[4];
  const float* b1    = (const float*)d_in[5];
  const float* w2    = (const float*)d_in[6];

  float* out_vec = (float*)d_out;                       // (8,128,512)
  float* out_w   = out_vec + (size_t)B_ * Q_ * D_;      // (8,128,256)

  float* qp  = (float*)d_ws;                            // (8,128,512) = 2 MB
  float* kpb = qp + (size_t)B_ * Q_ * D_;               // (8,256,512) = 4 MB

  proj_kernel<<<(B_ * Q_ + B_ * K_) / 8, 256, 0, stream>>>(query, key, W1, b1, qp, kpb);
  attn_kernel<<<dim3(Q_ / 2, B_), 256, 0, stream>>>(qp, kpb, value, mask, w2, out_vec, out_w);
}

// Round 2
// 168.685 us; speedup vs baseline: 1.1165x; 1.1165x over previous
//
#include <hip/hip_runtime.h>
#include <hip/hip_bf16.h>

#define B_ 8
#define Q_ 128
#define K_ 256
#define D_ 512
#define TWOLOG2E 2.8853900817779268f
#define SCALE 0.044194173824159216f   // 1/sqrt(512)
#define L2E 1.4426950408889634f
#define MASKVAL (-44194173.824159216f) // -1e9 * SCALE

#if __has_builtin(__builtin_amdgcn_exp2f)
#define EX2 __builtin_amdgcn_exp2f
#else
#define EX2 exp2f
#endif
#if __has_builtin(__builtin_amdgcn_rcpf)
#define RCP __builtin_amdgcn_rcpf
#else
#define RCP(x) (1.0f / (x))
#endif

// ---------------- Kernel 1: projections (fp32 VALU) ----------------
// Computes qp2 = 2log2e * (query @ Wq), kpb2 = 2log2e * (key @ Wk + b1).
// Block: 16 rows x 256 cols. Grid = 192 row-tiles x 2 col-tiles = 384.
// Per thread: 4 rows x 4 cols. W loads float4-coalesced; X rows via
// wave-uniform indices -> scalar loads (off the VALU pipe).
__global__ __launch_bounds__(256) void proj_kernel(
    const float* __restrict__ query, const float* __restrict__ key,
    const float* __restrict__ W1, const float* __restrict__ b1,
    float* __restrict__ qp, float* __restrict__ kpb) {
  const int t = threadIdx.x;
  const int rt = blockIdx.x >> 1;  // row tile (16 rows)
  const int ct = blockIdx.x & 1;   // col tile (256 cols)
  const int R0 = rt * 16;
  const bool is_k = R0 >= B_ * Q_;
  const float* X = is_k ? key : query;
  const int row0 = is_k ? (R0 - B_ * Q_) : R0;
  const float* W = W1 + (is_k ? (size_t)D_ * D_ : 0);
  float* out = is_k ? kpb : qp;

  const int rg = __builtin_amdgcn_readfirstlane(t >> 6);  // wave 0..3 -> rows 4rg..4rg+3
  const int tc = t & 63;
  const int col = ct * 256 + tc * 4;

  const float* Xr = X + (size_t)(row0 + rg * 4) * D_;

  float4 acc[4];
#pragma unroll
  for (int r = 0; r < 4; ++r) acc[r] = make_float4(0.f, 0.f, 0.f, 0.f);

  for (int d = 0; d < D_; d += 4) {
    float4 wv[4];
#pragma unroll
    for (int dd = 0; dd < 4; ++dd)
      wv[dd] = *(const float4*)&W[(size_t)(d + dd) * D_ + col];
#pragma unroll
    for (int r = 0; r < 4; ++r) {
#pragma unroll
      for (int dd = 0; dd < 4; ++dd) {
        float x = Xr[(size_t)r * D_ + d + dd];  // uniform -> s_load
        acc[r].x = fmaf(x, wv[dd].x, acc[r].x);
        acc[r].y = fmaf(x, wv[dd].y, acc[r].y);
        acc[r].z = fmaf(x, wv[dd].z, acc[r].z);
        acc[r].w = fmaf(x, wv[dd].w, acc[r].w);
      }
    }
  }
  float4 bias = make_float4(0.f, 0.f, 0.f, 0.f);
  if (is_k) bias = *(const float4*)&b1[col];
#pragma unroll
  for (int r = 0; r < 4; ++r) {
    float4 o;
    o.x = (acc[r].x + bias.x) * TWOLOG2E;
    o.y = (acc[r].y + bias.y) * TWOLOG2E;
    o.z = (acc[r].z + bias.z) * TWOLOG2E;
    o.w = (acc[r].w + bias.w) * TWOLOG2E;
    *(float4*)&out[(size_t)(row0 + rg * 4 + r) * D_ + col] = o;
  }
}

// ---------------- Kernel 2: fused tanh-score + softmax + PV ----------------
// Block: 512 threads = 8 waves, handles (b, q0..q0+1). Grid (64, 8) = 512 blocks.
// Wave w: k-range (w&3)*64 (lane = k), h-half (w>>2)*256. No cross-lane
// reductions in the hot loop; kpb staged in XOR-swizzled LDS (2-way banks);
// qp/w2 via wave-uniform indices -> scalar loads.
__global__ __launch_bounds__(512) void attn_kernel(
    const float* __restrict__ qp, const float* __restrict__ kpb,
    const float* __restrict__ value, const int* __restrict__ mask,
    const float* __restrict__ w2,
    float* __restrict__ out_vec, float* __restrict__ out_w) {
  __shared__ float smem[8 * 2048];  // 64 KB: 8 wave-regions of 64k x 32h
  const int b = blockIdx.y;
  const int q0 = blockIdx.x * 2;
  const int t = threadIdx.x;
  const int lane = t & 63;
  const int w = __builtin_amdgcn_readfirstlane(t >> 6);  // 0..7
  const int k0 = (w & 3) * 64;
  const int habs = (w >> 2) * 256;

  float* reg = smem + w * 2048;
  const float* kb = kpb + (size_t)(b * K_ + k0) * D_ + habs;
  const float* qa = qp + (size_t)(b * Q_ + q0) * D_ + habs;  // uniform
  const float* qb = qa + D_;
  const float* w2h = w2 + habs;

  const int r8 = lane >> 3;
  const int c4 = lane & 7;
  const int lx = lane & 31;

  float acc0 = 0.f, acc1 = 0.f;

  for (int hc = 0; hc < 256; hc += 32) {
    // stage 64 k-rows x 32 h (wave-private region, no barrier needed)
#pragma unroll
    for (int it = 0; it < 8; ++it) {
      int row = r8 + it * 8;
      float4 v = *(const float4*)&kb[(size_t)row * D_ + hc + c4 * 4];
      int rx = row & 31;
      int base = row * 32;
      reg[base + ((c4 * 4 + 0) ^ rx)] = v.x;
      reg[base + ((c4 * 4 + 1) ^ rx)] = v.y;
      reg[base + ((c4 * 4 + 2) ^ rx)] = v.z;
      reg[base + ((c4 * 4 + 3) ^ rx)] = v.w;
    }
#pragma unroll
    for (int h = 0; h < 32; ++h) {
      float kv = reg[lane * 32 + (h ^ lx)];
      float wv = w2h[hc + h];        // uniform -> s_load
      float x0 = qa[hc + h] + kv;    // uniform -> s_load
      float x1 = qb[hc + h] + kv;
      float e0 = EX2(x0);            // e^{2(qp+kp+b1)} via prescale
      float e1 = EX2(x1);
      float th0 = fmaf(-2.f, RCP(e0 + 1.f), 1.f);
      float th1 = fmaf(-2.f, RCP(e1 + 1.f), 1.f);
      acc0 = fmaf(wv, th0, acc0);
      acc1 = fmaf(wv, th1, acc1);
    }
  }
  // partial scores (h-half) into own region
  reg[lane] = acc0;
  reg[64 + lane] = acc1;
  __syncthreads();

  // softmax: wave 0 -> q0, wave 1 -> q0+1
  if (w < 2) {
    const int q = w;
    float s[4];
#pragma unroll
    for (int r = 0; r < 4; ++r) {
      float part = smem[r * 2048 + q * 64 + lane] +
                   smem[(r + 4) * 2048 + q * 64 + lane];
      int mk = mask[b * K_ + r * 64 + lane];
      s[r] = mk ? MASKVAL : part * SCALE;
    }
    float mx = fmaxf(fmaxf(s[0], s[1]), fmaxf(s[2], s[3]));
#pragma unroll
    for (int off = 32; off; off >>= 1) mx = fmaxf(mx, __shfl_xor(mx, off));
    float e[4], sum = 0.f;
#pragma unroll
    for (int r = 0; r < 4; ++r) {
      e[r] = EX2((s[r] - mx) * L2E);
      sum += e[r];
    }
#pragma unroll
    for (int off = 32; off; off >>= 1) sum += __shfl_xor(sum, off);
    float inv = RCP(sum);
    float* ow = out_w + (size_t)(b * Q_ + q0 + q) * K_;
#pragma unroll
    for (int r = 0; r < 4; ++r) {
      float p = e[r] * inv;
      smem[r * 2048 + q * 64 + lane] = p;  // final weights for PV
      ow[r * 64 + lane] = p;
    }
  }
  __syncthreads();

  // PV: 512 threads, col = t; p via float4 LDS broadcasts
  float o0 = 0.f, o1 = 0.f;
  const float* vb = value + (size_t)b * K_ * D_;
  for (int k = 0; k < K_; k += 4) {
    float4 p0 = *(const float4*)&smem[(k >> 6) * 2048 + (k & 63)];
    float4 p1 = *(const float4*)&smem[(k >> 6) * 2048 + 64 + (k & 63)];
    float v0 = vb[(size_t)(k + 0) * D_ + t];
    float v1 = vb[(size_t)(k + 1) * D_ + t];
    float v2 = vb[(size_t)(k + 2) * D_ + t];
    float v3 = vb[(size_t)(k + 3) * D_ + t];
    o0 = fmaf(p0.x, v0, fmaf(p0.y, v1, fmaf(p0.z, v2, fmaf(p0.w, v3, o0))));
    o1 = fmaf(p1.x, v0, fmaf(p1.y, v1, fmaf(p1.z, v2, fmaf(p1.w, v3, o1))));
  }
  out_vec[(size_t)(b * Q_ + q0) * D_ + t] = o0;
  out_vec[(size_t)(b * Q_ + q0 + 1) * D_ + t] = o1;
}

extern "C" void kernel_launch(void* const* d_in, const int* in_sizes, int n_in,
                              void* d_out, int out_size, void* d_ws, size_t ws_size,
                              hipStream_t stream) {
  const float* query = (const float*)d_in[0];
  const float* key   = (const float*)d_in[1];
  const float* value = (const float*)d_in[2];
  const int*   mask  = (const int*)d_in[3];
  const float* W1    = (const float*)d_in[4];
  const float* b1    = (const float*)d_in[5];
  const float* w2    = (const float*)d_in[6];

  float* out_vec = (float*)d_out;                   // (8,128,512)
  float* out_w   = out_vec + (size_t)B_ * Q_ * D_;  // (8,128,256)

  float* qp  = (float*)d_ws;                        // 2 MB (pre-scaled)
  float* kpb = qp + (size_t)B_ * Q_ * D_;           // 4 MB (pre-scaled, +b1)

  proj_kernel<<<384, 256, 0, stream>>>(query, key, W1, b1, qp, kpb);
  attn_kernel<<<dim3(Q_ / 2, B_), 512, 0, stream>>>(qp, kpb, value, mask, w2,
                                                    out_vec, out_w);
}

// Round 3
// 134.615 us; speedup vs baseline: 1.3991x; 1.2531x over previous
//
#include <hip/hip_runtime.h>
#include <hip/hip_bf16.h>

#define B_ 8
#define Q_ 128
#define K_ 256
#define D_ 512
#define TWOLOG2E 2.8853900817779268f
#define SCALE 0.044194173824159216f   // 1/sqrt(512)
#define L2E 1.4426950408889634f
#define MASKVAL (-44194173.824159216f) // -1e9 * SCALE

typedef __attribute__((ext_vector_type(8))) short frag8;   // 8 bf16
typedef __attribute__((ext_vector_type(4))) float f32x4;

__device__ __forceinline__ float fexp2(float x) {
  float r;
  asm("v_exp_f32 %0, %1" : "=v"(r) : "v"(x));
  return r;
}
__device__ __forceinline__ float frcp(float x) {
  float r;
  asm("v_rcp_f32 %0, %1" : "=v"(r) : "v"(x));
  return r;
}
__device__ __forceinline__ unsigned short f2bf(float x) {
  unsigned u = __float_as_uint(x);
  unsigned r = u + 0x7FFFu + ((u >> 16) & 1u);
  return (unsigned short)(r >> 16);
}

// ---------------- Kernel 0: prep ----------------
// blocks 0..767: Xb[r][d] = bf16(concat(query,key)[r][d]), r in [0,3072)
// blocks 768..895: WT[half*512+h][d] = bf16(W1[half*512+d][h])
__global__ __launch_bounds__(256) void prep_kernel(
    const float* __restrict__ query, const float* __restrict__ key,
    const float* __restrict__ W1,
    unsigned short* __restrict__ Xb, unsigned short* __restrict__ WT) {
  const int t = threadIdx.x;
  if (blockIdx.x < 768) {
    const int r = blockIdx.x * 4 + (t >> 6);
    const int col = (t & 63) * 8;
    const float* src = (r < 1024) ? (query + (size_t)r * D_)
                                  : (key + (size_t)(r - 1024) * D_);
    float4 a = *(const float4*)(src + col);
    float4 b = *(const float4*)(src + col + 4);
    union { frag8 f; unsigned short u[8]; } o;
    o.u[0] = f2bf(a.x); o.u[1] = f2bf(a.y); o.u[2] = f2bf(a.z); o.u[3] = f2bf(a.w);
    o.u[4] = f2bf(b.x); o.u[5] = f2bf(b.y); o.u[6] = f2bf(b.z); o.u[7] = f2bf(b.w);
    *(frag8*)(Xb + (size_t)r * D_ + col) = o.f;
  } else {
    __shared__ float ld[64][65];
    const int j = blockIdx.x - 768;
    const int half = j >> 6;
    const int dt = (j >> 3) & 7;
    const int ht = j & 7;
    const int d0 = dt * 64, h0 = ht * 64;
    const int dr = t >> 2, c = t & 3;
    const float* wrow = W1 + (size_t)(half * 512 + d0 + dr) * D_ + h0 + c * 16;
#pragma unroll
    for (int jj = 0; jj < 16; ++jj) ld[dr][c * 16 + jj] = wrow[jj];
    __syncthreads();
    const int hr = t >> 2;
    union { frag8 f; unsigned short u[8]; } o0, o1;
#pragma unroll
    for (int jj = 0; jj < 8; ++jj) o0.u[jj] = f2bf(ld[c * 16 + jj][hr]);
#pragma unroll
    for (int jj = 0; jj < 8; ++jj) o1.u[jj] = f2bf(ld[c * 16 + 8 + jj][hr]);
    unsigned short* dst = WT + (size_t)(half * 512 + h0 + hr) * D_ + d0 + c * 16;
    *(frag8*)dst = o0.f;
    *(frag8*)(dst + 8) = o1.f;
  }
}

// ---------------- Kernel 1: MFMA projection GEMM ----------------
// C[m][n] = sum_k Xb[m][k] * WT[sel(m)*512 + n][k]; epilogue adds b1 (k rows)
// and scales by 2log2e. Tiles 64x64, K-steps of 32, 256 threads (4 waves).
__global__ __launch_bounds__(256) void gemm_kernel(
    const unsigned short* __restrict__ Xb, const unsigned short* __restrict__ WT,
    const float* __restrict__ b1,
    float* __restrict__ qp, float* __restrict__ kpb) {
  __shared__ short As[64 * 32];
  __shared__ short Bs[64 * 32];
  const int t = threadIdx.x;
  const int m0 = blockIdx.y * 64;
  const int n0 = blockIdx.x * 64;
  const bool is_k = (m0 >= B_ * Q_);

  // staging: thread t -> row t>>2, chunk c = t&3 (8 bf16), swizzled by row
  const int srow = t >> 2;
  const int sc = t & 3;
  const int sst = srow * 32 + ((sc ^ ((srow >> 1) & 3)) * 8);
  const unsigned short* gA = Xb + (size_t)(m0 + srow) * D_ + sc * 8;
  const unsigned short* gB = WT + (size_t)((is_k ? 512 : 0) + n0 + srow) * D_ + sc * 8;

  // fragment read offsets
  const int l = t & 63;
  const int w = t >> 6;
  const int lr = l & 15;
  const int kg = l >> 4;
  const int swz = (kg ^ ((lr >> 1) & 3)) * 8;
  int aoff[4];
#pragma unroll
  for (int mt = 0; mt < 4; ++mt) aoff[mt] = (mt * 16 + lr) * 32 + swz;
  const int boff = (w * 16 + lr) * 32 + swz;

  f32x4 acc[4];
#pragma unroll
  for (int mt = 0; mt < 4; ++mt) acc[mt] = (f32x4){0.f, 0.f, 0.f, 0.f};

  for (int k0 = 0; k0 < D_; k0 += 32) {
    frag8 av = *(const frag8*)(gA + k0);
    frag8 bv = *(const frag8*)(gB + k0);
    __syncthreads();
    *(frag8*)(As + sst) = av;
    *(frag8*)(Bs + sst) = bv;
    __syncthreads();
    frag8 bf = *(const frag8*)(Bs + boff);
#pragma unroll
    for (int mt = 0; mt < 4; ++mt) {
      frag8 af = *(const frag8*)(As + aoff[mt]);
      acc[mt] = __builtin_amdgcn_mfma_f32_16x16x32_bf16(af, bf, acc[mt], 0, 0, 0);
    }
  }

  const int col = n0 + w * 16 + lr;
  const float bc = is_k ? b1[col] : 0.f;
#pragma unroll
  for (int mt = 0; mt < 4; ++mt) {
#pragma unroll
    for (int i = 0; i < 4; ++i) {
      const int row = m0 + mt * 16 + kg * 4 + i;
      const float val = (acc[mt][i] + bc) * TWOLOG2E;
      if (is_k)
        kpb[(size_t)(row - B_ * Q_) * D_ + col] = val;
      else
        qp[(size_t)row * D_ + col] = val;
    }
  }
}

// ---------------- Kernel 2: fused tanh-score + softmax + PV ----------------
__global__ __launch_bounds__(512) void attn_kernel(
    const float* __restrict__ qp, const float* __restrict__ kpb,
    const float* __restrict__ value, const int* __restrict__ mask,
    const float* __restrict__ w2,
    float* __restrict__ out_vec, float* __restrict__ out_w) {
  __shared__ float smem[8 * 2048];  // 64 KB
  const int b = blockIdx.y;
  const int q0 = blockIdx.x * 2;
  const int t = threadIdx.x;
  const int lane = t & 63;
  const int w = __builtin_amdgcn_readfirstlane(t >> 6);
  const int k0 = (w & 3) * 64;
  const int habs = (w >> 2) * 256;

  float* reg = smem + w * 2048;
  const float* kb = kpb + (size_t)(b * K_ + k0) * D_ + habs;
  const float* qa = qp + (size_t)(b * Q_ + q0) * D_ + habs;  // uniform
  const float* qb = qa + D_;
  const float* w2h = w2 + habs;

  const int r8 = lane >> 3;
  const int c4 = lane & 7;
  const int lx = lane & 31;

  float acc0 = 0.f, acc1 = 0.f;

  for (int hc = 0; hc < 256; hc += 32) {
#pragma unroll
    for (int it = 0; it < 8; ++it) {
      int row = r8 + it * 8;
      float4 v = *(const float4*)&kb[(size_t)row * D_ + hc + c4 * 4];
      int rx = row & 31;
      int base = row * 32;
      reg[base + ((c4 * 4 + 0) ^ rx)] = v.x;
      reg[base + ((c4 * 4 + 1) ^ rx)] = v.y;
      reg[base + ((c4 * 4 + 2) ^ rx)] = v.z;
      reg[base + ((c4 * 4 + 3) ^ rx)] = v.w;
    }
#pragma unroll
    for (int hh = 0; hh < 32; hh += 16) {
      float qaC[16], qbC[16], wC[16];
#pragma unroll
      for (int j = 0; j < 16; ++j) {
        qaC[j] = qa[hc + hh + j];
        qbC[j] = qb[hc + hh + j];
        wC[j] = w2h[hc + hh + j];
      }
#pragma unroll
      for (int j = 0; j < 16; ++j) {
        const int h = hh + j;
        float kv = reg[lane * 32 + (h ^ lx)];
        float e0 = fexp2(qaC[j] + kv);   // prescaled by 2*log2(e)
        float e1 = fexp2(qbC[j] + kv);
        float r0 = frcp(e0 + 1.f);
        float r1 = frcp(e1 + 1.f);
        acc0 = fmaf(wC[j], fmaf(-2.f, r0, 1.f), acc0);
        acc1 = fmaf(wC[j], fmaf(-2.f, r1, 1.f), acc1);
      }
    }
  }
  reg[lane] = acc0;
  reg[64 + lane] = acc1;
  __syncthreads();

  if (w < 2) {
    const int q = w;
    float s[4];
#pragma unroll
    for (int r = 0; r < 4; ++r) {
      float part = smem[r * 2048 + q * 64 + lane] +
                   smem[(r + 4) * 2048 + q * 64 + lane];
      int mk = mask[b * K_ + r * 64 + lane];
      s[r] = mk ? MASKVAL : part * SCALE;
    }
    float mx = fmaxf(fmaxf(s[0], s[1]), fmaxf(s[2], s[3]));
#pragma unroll
    for (int off = 32; off; off >>= 1) mx = fmaxf(mx, __shfl_xor(mx, off));
    float e[4], sum = 0.f;
#pragma unroll
    for (int r = 0; r < 4; ++r) {
      e[r] = fexp2((s[r] - mx) * L2E);
      sum += e[r];
    }
#pragma unroll
    for (int off = 32; off; off >>= 1) sum += __shfl_xor(sum, off);
    float inv = frcp(sum);
    float* ow = out_w + (size_t)(b * Q_ + q0 + q) * K_;
#pragma unroll
    for (int r = 0; r < 4; ++r) {
      float p = e[r] * inv;
      smem[r * 2048 + q * 64 + lane] = p;
      ow[r * 64 + lane] = p;
    }
  }
  __syncthreads();

  float o0 = 0.f, o1 = 0.f;
  const float* vb = value + (size_t)b * K_ * D_;
  for (int k = 0; k < K_; k += 4) {
    float4 p0 = *(const float4*)&smem[(k >> 6) * 2048 + (k & 63)];
    float4 p1 = *(const float4*)&smem[(k >> 6) * 2048 + 64 + (k & 63)];
    float v0 = vb[(size_t)(k + 0) * D_ + t];
    float v1 = vb[(size_t)(k + 1) * D_ + t];
    float v2 = vb[(size_t)(k + 2) * D_ + t];
    float v3 = vb[(size_t)(k + 3) * D_ + t];
    o0 = fmaf(p0.x, v0, fmaf(p0.y, v1, fmaf(p0.z, v2, fmaf(p0.w, v3, o0))));
    o1 = fmaf(p1.x, v0, fmaf(p1.y, v1, fmaf(p1.z, v2, fmaf(p1.w, v3, o1))));
  }
  out_vec[(size_t)(b * Q_ + q0) * D_ + t] = o0;
  out_vec[(size_t)(b * Q_ + q0 + 1) * D_ + t] = o1;
}

extern "C" void kernel_launch(void* const* d_in, const int* in_sizes, int n_in,
                              void* d_out, int out_size, void* d_ws, size_t ws_size,
                              hipStream_t stream) {
  const float* query = (const float*)d_in[0];
  const float* key   = (const float*)d_in[1];
  const float* value = (const float*)d_in[2];
  const int*   mask  = (const int*)d_in[3];
  const float* W1    = (const float*)d_in[4];
  const float* b1    = (const float*)d_in[5];
  const float* w2    = (const float*)d_in[6];

  float* out_vec = (float*)d_out;                   // (8,128,512)
  float* out_w   = out_vec + (size_t)B_ * Q_ * D_;  // (8,128,256)

  float* qp  = (float*)d_ws;                           // 2 MB fp32
  float* kpb = qp + (size_t)B_ * Q_ * D_;              // 4 MB fp32
  unsigned short* Xb = (unsigned short*)(kpb + (size_t)B_ * K_ * D_);  // 3 MB bf16
  unsigned short* WT = Xb + (size_t)3072 * D_;         // 1 MB bf16

  prep_kernel<<<896, 256, 0, stream>>>(query, key, W1, Xb, WT);
  gemm_kernel<<<dim3(8, 48), 256, 0, stream>>>(Xb, WT, b1, qp, kpb);
  attn_kernel<<<dim3(Q_ / 2, B_), 512, 0, stream>>>(qp, kpb, value, mask, w2,
                                                    out_vec, out_w);
}

// Round 4
// 121.636 us; speedup vs baseline: 1.5484x; 1.1067x over previous
//
#include <hip/hip_runtime.h>
#include <hip/hip_bf16.h>

#define B_ 8
#define Q_ 128
#define K_ 256
#define D_ 512
#define TWOLOG2E 2.8853900817779268f
#define SCALE 0.044194173824159216f   // 1/sqrt(512)
#define L2E 1.4426950408889634f
#define MASKVAL (-44194173.824159216f) // -1e9 * SCALE

typedef __attribute__((ext_vector_type(8))) short frag8;   // 8 bf16
typedef __attribute__((ext_vector_type(4))) float f32x4;

__device__ __forceinline__ float fexp2(float x) {
  float r;
  asm("v_exp_f32 %0, %1" : "=v"(r) : "v"(x));
  return r;
}
__device__ __forceinline__ float frcp(float x) {
  float r;
  asm("v_rcp_f32 %0, %1" : "=v"(r) : "v"(x));
  return r;
}
__device__ __forceinline__ unsigned short f2bf(float x) {
  unsigned u = __float_as_uint(x);
  unsigned r = u + 0x7FFFu + ((u >> 16) & 1u);
  return (unsigned short)(r >> 16);
}

// ---------------- Kernel 0: prep ----------------
// blocks 0..767 : Xb[r][d] = bf16(concat(query,key)[r][d]), r in [0,3072)
// blocks 768..1023: WT[hrow][d] = bf16(W1[(hrow>>9)*512 + d][hrow&511])
//   (row-gather: for each d-step j, lanes read 64 consecutive h -> coalesced)
__global__ __launch_bounds__(256) void prep_kernel(
    const float* __restrict__ query, const float* __restrict__ key,
    const float* __restrict__ W1,
    unsigned short* __restrict__ Xb, unsigned short* __restrict__ WT) {
  const int t = threadIdx.x;
  if (blockIdx.x < 768) {
    const int r = blockIdx.x * 4 + (t >> 6);
    const int col = (t & 63) * 8;
    const float* src = (r < 1024) ? (query + (size_t)r * D_)
                                  : (key + (size_t)(r - 1024) * D_);
    float4 a = *(const float4*)(src + col);
    float4 b = *(const float4*)(src + col + 4);
    union { frag8 f; unsigned short u[8]; } o;
    o.u[0] = f2bf(a.x); o.u[1] = f2bf(a.y); o.u[2] = f2bf(a.z); o.u[3] = f2bf(a.w);
    o.u[4] = f2bf(b.x); o.u[5] = f2bf(b.y); o.u[6] = f2bf(b.z); o.u[7] = f2bf(b.w);
    *(frag8*)(Xb + (size_t)r * D_ + col) = o.f;
  } else {
    const int bi2 = blockIdx.x - 768;   // 0..255
    const int cd = bi2 >> 2;            // d-chunk 0..63
    const int hrow = (bi2 & 3) * 256 + t;  // 0..1023
    const int half = hrow >> 9;
    const int h = hrow & 511;
    const float* src = W1 + ((size_t)(half * 512 + cd * 8)) * D_ + h;
    union { frag8 f; unsigned short u[8]; } o;
#pragma unroll
    for (int j = 0; j < 8; ++j) o.u[j] = f2bf(src[(size_t)j * D_]);
    *(frag8*)(WT + (size_t)hrow * D_ + cd * 8) = o.f;
  }
}

// ---------------- Kernel 1: MFMA projection GEMM ----------------
// C[m][n] = sum_k Xb[m][k]*WT[sel(m)*512+n][k].
// q-rows (m<1024): qp[m][n] = C*2log2e            (row-major [b][q][h])
// k-rows         : kpbT[b][n(h)][k] = (C+b1)*2log2e  (TRANSPOSED, k-contiguous)
// Tiles 64x64, BK=64, 256 threads (4 waves), reg-prefetch + 3-bit xor swizzle.
__global__ __launch_bounds__(256) void gemm_kernel(
    const unsigned short* __restrict__ Xb, const unsigned short* __restrict__ WT,
    const float* __restrict__ b1,
    float* __restrict__ qp, float* __restrict__ kpbT) {
  __shared__ short As[64 * 64];
  __shared__ short Bs[64 * 64];
  const int t = threadIdx.x;
  const int m0 = blockIdx.y * 64;
  const int n0 = blockIdx.x * 64;
  const bool is_k = (m0 >= B_ * Q_);

  const int srow = t >> 2;        // 0..63
  const int sc = t & 3;           // chunk 0..3 (and +4)
  const int skey = srow & 7;
  const int wp0 = srow * 64 + ((sc ^ skey) * 8);
  const int wp1 = srow * 64 + (((sc + 4) ^ skey) * 8);
  const unsigned short* gA = Xb + (size_t)(m0 + srow) * D_ + sc * 8;
  const unsigned short* gB = WT + (size_t)((is_k ? 512 : 0) + n0 + srow) * D_ + sc * 8;

  const int l = t & 63;
  const int w = t >> 6;
  const int lr = l & 15;
  const int kg = l >> 4;
  const int rk = lr & 7;          // (row & 7) for all frag rows
  int aoff[4][2], boff[2];
#pragma unroll
  for (int kk = 0; kk < 2; ++kk) {
    const int cpos = ((kk * 4 + kg) ^ rk) * 8;
#pragma unroll
    for (int mt = 0; mt < 4; ++mt) aoff[mt][kk] = (mt * 16 + lr) * 64 + cpos;
    boff[kk] = (w * 16 + lr) * 64 + cpos;
  }

  f32x4 acc[4];
#pragma unroll
  for (int mt = 0; mt < 4; ++mt) acc[mt] = (f32x4){0.f, 0.f, 0.f, 0.f};

  for (int k0 = 0; k0 < D_; k0 += 64) {
    frag8 a0 = *(const frag8*)(gA + k0);
    frag8 a1 = *(const frag8*)(gA + k0 + 32);
    frag8 b0 = *(const frag8*)(gB + k0);
    frag8 b1v = *(const frag8*)(gB + k0 + 32);
    __syncthreads();
    *(frag8*)(As + wp0) = a0;
    *(frag8*)(As + wp1) = a1;
    *(frag8*)(Bs + wp0) = b0;
    *(frag8*)(Bs + wp1) = b1v;
    __syncthreads();
#pragma unroll
    for (int kk = 0; kk < 2; ++kk) {
      frag8 bf = *(const frag8*)(Bs + boff[kk]);
#pragma unroll
      for (int mt = 0; mt < 4; ++mt) {
        frag8 af = *(const frag8*)(As + aoff[mt][kk]);
        acc[mt] = __builtin_amdgcn_mfma_f32_16x16x32_bf16(af, bf, acc[mt], 0, 0, 0);
      }
    }
  }

  const int col = n0 + w * 16 + lr;   // n (h)
  if (is_k) {
    const float bc = b1[col];
#pragma unroll
    for (int mt = 0; mt < 4; ++mt) {
      const int krow = m0 - B_ * Q_ + mt * 16 + kg * 4;  // 4 consecutive k
      const int bb = krow >> 8;
      const int kk = krow & 255;
      float4 v;
      v.x = (acc[mt][0] + bc) * TWOLOG2E;
      v.y = (acc[mt][1] + bc) * TWOLOG2E;
      v.z = (acc[mt][2] + bc) * TWOLOG2E;
      v.w = (acc[mt][3] + bc) * TWOLOG2E;
      *(float4*)&kpbT[((size_t)bb * D_ + col) * K_ + kk] = v;
    }
  } else {
#pragma unroll
    for (int mt = 0; mt < 4; ++mt) {
#pragma unroll
      for (int i = 0; i < 4; ++i) {
        const int row = m0 + mt * 16 + kg * 4 + i;
        qp[(size_t)row * D_ + col] = acc[mt][i] * TWOLOG2E;
      }
    }
  }
}

// ---------------- Kernel 2: fused tanh-score + softmax + PV ----------------
// 1024 threads = 16 waves, 4 q-rows/block, grid (32, 8).
// Wave w: kc = w&3 (k-range kc*64+lane), hq = w>>2 (h-range hq*128).
// Inner loop: 1 coalesced kv load + per q: add, exp2, rcp, fma (q-side in SGPRs).
__global__ __launch_bounds__(1024) void attn_kernel(
    const float* __restrict__ qp, const float* __restrict__ kpbT,
    const float* __restrict__ value, const int* __restrict__ mask,
    const float* __restrict__ w2,
    float* __restrict__ out_vec, float* __restrict__ out_w) {
  __shared__ float smem_p[16 * 256];  // partials: [w][q(4)][64]
  __shared__ float pw[4 * 256];       // final weights: [q][k]
  const int b = blockIdx.y;
  const int q0 = blockIdx.x * 4;
  const int t = threadIdx.x;
  const int lane = t & 63;
  const int w = __builtin_amdgcn_readfirstlane(t >> 6);  // 0..15
  const int kc = w & 3;
  const int hq = w >> 2;

  // ---- phase 1: partial sums of w2[h] * r(h,k,q) over this wave's h-range
  {
    const float* pk = kpbT + ((size_t)b * D_ + hq * 128) * K_ + kc * 64 + lane;
    const float* q_0 = qp + (size_t)(b * Q_ + q0 + 0) * D_ + hq * 128;
    const float* q_1 = qp + (size_t)(b * Q_ + q0 + 1) * D_ + hq * 128;
    const float* q_2 = qp + (size_t)(b * Q_ + q0 + 2) * D_ + hq * 128;
    const float* q_3 = qp + (size_t)(b * Q_ + q0 + 3) * D_ + hq * 128;
    const float* w2h = w2 + hq * 128;

    float a0 = 0.f, a1 = 0.f, a2 = 0.f, a3 = 0.f;
    for (int h = 0; h < 128; h += 8) {
      float kv[8];
#pragma unroll
      for (int j = 0; j < 8; ++j) kv[j] = pk[(size_t)(h + j) * K_];
#pragma unroll
      for (int j = 0; j < 8; ++j) {
        const float wv = w2h[h + j];
        const float r0 = frcp(fexp2(q_0[h + j] + kv[j]) + 1.f);
        const float r1 = frcp(fexp2(q_1[h + j] + kv[j]) + 1.f);
        const float r2 = frcp(fexp2(q_2[h + j] + kv[j]) + 1.f);
        const float r3 = frcp(fexp2(q_3[h + j] + kv[j]) + 1.f);
        a0 = fmaf(wv, r0, a0);
        a1 = fmaf(wv, r1, a1);
        a2 = fmaf(wv, r2, a2);
        a3 = fmaf(wv, r3, a3);
      }
    }
    smem_p[w * 256 + 0 * 64 + lane] = a0;
    smem_p[w * 256 + 1 * 64 + lane] = a1;
    smem_p[w * 256 + 2 * 64 + lane] = a2;
    smem_p[w * 256 + 3 * 64 + lane] = a3;
  }
  __syncthreads();

  // ---- phase 2: combine + softmax; wave qi handles q-row q0+qi
  if (w < 4) {
    float sw = 0.f;
#pragma unroll
    for (int m = 0; m < 8; ++m) sw += w2[lane + 64 * m];
#pragma unroll
    for (int off = 32; off; off >>= 1) sw += __shfl_xor(sw, off);

    float s[4];
#pragma unroll
    for (int r = 0; r < 4; ++r) {  // r = kc
      float p = smem_p[(0 * 4 + r) * 256 + w * 64 + lane] +
                smem_p[(1 * 4 + r) * 256 + w * 64 + lane] +
                smem_p[(2 * 4 + r) * 256 + w * 64 + lane] +
                smem_p[(3 * 4 + r) * 256 + w * 64 + lane];
      const int mk = mask[b * K_ + r * 64 + lane];
      s[r] = mk ? MASKVAL : fmaf(-2.f, p, sw) * SCALE;
    }
    float mx = fmaxf(fmaxf(s[0], s[1]), fmaxf(s[2], s[3]));
#pragma unroll
    for (int off = 32; off; off >>= 1) mx = fmaxf(mx, __shfl_xor(mx, off));
    float e[4], sum = 0.f;
#pragma unroll
    for (int r = 0; r < 4; ++r) {
      e[r] = fexp2((s[r] - mx) * L2E);
      sum += e[r];
    }
#pragma unroll
    for (int off = 32; off; off >>= 1) sum += __shfl_xor(sum, off);
    const float inv = frcp(sum);
    float* ow = out_w + (size_t)(b * Q_ + q0 + w) * K_;
#pragma unroll
    for (int r = 0; r < 4; ++r) {
      const float p = e[r] * inv;
      pw[w * 256 + r * 64 + lane] = p;
      ow[r * 64 + lane] = p;
    }
  }
  __syncthreads();

  // ---- phase 3: PV. thread t -> col = t&511, q-pair qq = t>>9
  const int col = t & 511;
  const int qq = t >> 9;
  float o0 = 0.f, o1 = 0.f;
  const float* vb = value + (size_t)b * K_ * D_;
  for (int k = 0; k < K_; k += 4) {
    const float4 p0 = *(const float4*)&pw[(qq * 2 + 0) * 256 + k];
    const float4 p1 = *(const float4*)&pw[(qq * 2 + 1) * 256 + k];
    const float v0 = vb[(size_t)(k + 0) * D_ + col];
    const float v1 = vb[(size_t)(k + 1) * D_ + col];
    const float v2 = vb[(size_t)(k + 2) * D_ + col];
    const float v3 = vb[(size_t)(k + 3) * D_ + col];
    o0 = fmaf(p0.x, v0, fmaf(p0.y, v1, fmaf(p0.z, v2, fmaf(p0.w, v3, o0))));
    o1 = fmaf(p1.x, v0, fmaf(p1.y, v1, fmaf(p1.z, v2, fmaf(p1.w, v3, o1))));
  }
  out_vec[(size_t)(b * Q_ + q0 + qq * 2 + 0) * D_ + col] = o0;
  out_vec[(size_t)(b * Q_ + q0 + qq * 2 + 1) * D_ + col] = o1;
}

extern "C" void kernel_launch(void* const* d_in, const int* in_sizes, int n_in,
                              void* d_out, int out_size, void* d_ws, size_t ws_size,
                              hipStream_t stream) {
  const float* query = (const float*)d_in[0];
  const float* key   = (const float*)d_in[1];
  const float* value = (const float*)d_in[2];
  const int*   mask  = (const int*)d_in[3];
  const float* W1    = (const float*)d_in[4];
  const float* b1    = (const float*)d_in[5];
  const float* w2    = (const float*)d_in[6];

  float* out_vec = (float*)d_out;                   // (8,128,512)
  float* out_w   = out_vec + (size_t)B_ * Q_ * D_;  // (8,128,256)

  float* qp   = (float*)d_ws;                           // 2 MB fp32 [b][q][h]
  float* kpbT = qp + (size_t)B_ * Q_ * D_;              // 4 MB fp32 [b][h][k]
  unsigned short* Xb = (unsigned short*)(kpbT + (size_t)B_ * D_ * K_);  // 3 MB
  unsigned short* WT = Xb + (size_t)3072 * D_;          // 1 MB

  prep_kernel<<<1024, 256, 0, stream>>>(query, key, W1, Xb, WT);
  gemm_kernel<<<dim3(8, 48), 256, 0, stream>>>(Xb, WT, b1, qp, kpbT);
  attn_kernel<<<dim3(Q_ / 4, B_), 1024, 0, stream>>>(qp, kpbT, value, mask, w2,
                                                     out_vec, out_w);
}